// Round 13
// baseline (2918.931 us; speedup 1.0000x reference)
//
#include <hip/hip_runtime.h>

typedef unsigned int uint32;
typedef unsigned short ushort16;

typedef __attribute__((ext_vector_type(8))) short short8;
typedef __attribute__((ext_vector_type(4))) float f32x4;

// ---------------------------------------------------------------------------
// GNN: h1 = relu((x + mean_agg(x)) @ W1 + b1)
//      h2 = relu((h1 + mean_agg(h1)) @ W2 + b2)
//      out = h2 @ Wp + bp
//
// R24: push-style region aggregation — CSR eliminated.
//  R23 post-mortem: 1.6M scattered global deg atomics = 50MB write-amp, 69us
//  (cross-XCD line ping-pong; fire-and-forget doesn't help). Reverted.
//  New structure: regions of 256 nodes (R=391). Per-region f32 accumulator
//  in LDS (256x65 pad = 66.5KB -> 2 blocks/CU @1024t). One block per region
//  streams its packed rlist segment (src<<8|lt, 4B/edge), gathers source
//  half-rows (128B), atomicAdds into LDS acc; deg counted in-pass; output
//  h = in + acc/deg written coalesced. Two feature-half passes (A: 0-63 +
//  deg, B: 64-127). Deletes csr build+buffer, deg/start arrays, one rlist
//  pass. Prep = count/scan/scatter only; gemm1 fused into scatter launch.
//  Aggs' gather traffic identical to pull (3.45TB/s proven); declared risk:
//  LDS atomic throughput (~1M adds/CU) — revert if push_agg > 90us.
//  Pipeline: K1 count+Wt | K2 scan | K3 scatter||gemm1 | K4 pushagg1 |
//            K5 gemm2(biasrelu A-load) | K6 pushagg2 | K7 proj.
// ---------------------------------------------------------------------------

#define NRG2 256               // nodes per region
#define CAPP 5120              // rlist capacity per region (mean 4096, +16 sigma)
#define CHP  4096              // edges per count/scatter block
#define RSTR 400               // hist row stride (R=391)

__device__ __forceinline__ ushort16 f2bf(float f) {
    uint32 u = __float_as_uint(f);
    u += 0x7fffu + ((u >> 16) & 1u);       // round-to-nearest-even
    return (ushort16)(u >> 16);
}
__device__ __forceinline__ float bfhi(uint32 u) { return __uint_as_float(u & 0xffff0000u); }
__device__ __forceinline__ float bflo(uint32 u) { return __uint_as_float(u << 16); }
__device__ __forceinline__ uint32 pack2(float a, float b) {
    return (uint32)f2bf(a) | ((uint32)f2bf(b) << 16);
}

union U16 { uint4 u; short8 s; };
__device__ __forceinline__ short8 ld_frag(const ushort16* p) {
    U16 x; x.u = *(const uint4*)p; return x.s;
}

// ---------------------------------------------------------------------------
// K1: per-block region count (LDS only) + Wt prep on 16 extra blocks.
// ---------------------------------------------------------------------------
__global__ __launch_bounds__(256)
void count_prep_kernel(const int* __restrict__ tgt, int* __restrict__ hist,
                       const float* __restrict__ W1, const float* __restrict__ W2,
                       ushort16* __restrict__ Wt1, ushort16* __restrict__ Wt2,
                       int E, int PB, int R) {
    int tid = threadIdx.x, blk = blockIdx.x;
    if (blk >= PB) {   // Wt prep: 16 blocks, 2048 floats each, float4 loads
        int idx = blk - PB;
        const float* W = (idx >> 3) ? W2 : W1;
        ushort16* Wt = (idx >> 3) ? Wt2 : Wt1;
        int i0 = (idx & 7) * 2048 + tid * 8;
        float4 a = *(const float4*)(W + i0);
        float4 b = *(const float4*)(W + i0 + 4);
        int k = i0 >> 7, col = i0 & 127;
        Wt[(col + 0) * 128 + k] = f2bf(a.x);
        Wt[(col + 1) * 128 + k] = f2bf(a.y);
        Wt[(col + 2) * 128 + k] = f2bf(a.z);
        Wt[(col + 3) * 128 + k] = f2bf(a.w);
        Wt[(col + 4) * 128 + k] = f2bf(b.x);
        Wt[(col + 5) * 128 + k] = f2bf(b.y);
        Wt[(col + 6) * 128 + k] = f2bf(b.z);
        Wt[(col + 7) * 128 + k] = f2bf(b.w);
        return;
    }
    __shared__ int cnt[RSTR];
    for (int i = tid; i < RSTR; i += 256) cnt[i] = 0;
    __syncthreads();
    int q0 = blk * (CHP / 4), q1 = min(q0 + CHP / 4, E / 4);
    for (int q = q0 + tid; q < q1; q += 256) {
        int4 t = ((const int4*)tgt)[q];
        atomicAdd(&cnt[t.x >> 8], 1);
        atomicAdd(&cnt[t.y >> 8], 1);
        atomicAdd(&cnt[t.z >> 8], 1);
        atomicAdd(&cnt[t.w >> 8], 1);
    }
    if (blk == 0 && tid == 0)
        for (int e = (E / 4) * 4; e < E; ++e) atomicAdd(&cnt[tgt[e] >> 8], 1);
    __syncthreads();
    for (int i = tid; i < R; i += 256) hist[(size_t)blk * RSTR + i] = cnt[i];
}

// ---------------------------------------------------------------------------
// K2: per-region exclusive column scan of hist over PB blocks + total[r].
// ---------------------------------------------------------------------------
__global__ __launch_bounds__(256)
void scan_kernel(int* __restrict__ hist, int* __restrict__ total, int PB) {
    __shared__ int sd[256];
    __shared__ int carrySh;
    int r = blockIdx.x, tid = threadIdx.x;
    if (tid == 0) carrySh = 0;
    __syncthreads();
    int chunks = (PB + 255) >> 8;
    for (int ch = 0; ch < chunks; ++ch) {
        int g = ch * 256 + tid;
        int v = (g < PB) ? hist[(size_t)g * RSTR + r] : 0;
        int c0 = carrySh;
        sd[tid] = v;
        __syncthreads();
        for (int o = 1; o < 256; o <<= 1) {
            int t = (tid >= o) ? sd[tid - o] : 0;
            __syncthreads();
            sd[tid] += t;
            __syncthreads();
        }
        if (g < PB) hist[(size_t)g * RSTR + r] = sd[tid] - v + c0;
        int tot = sd[255];
        __syncthreads();
        if (tid == 0) carrySh = c0 + tot;
        __syncthreads();
    }
    if (tid == 0) total[r] = carrySh;
}

// ---------------------------------------------------------------------------
// GEMM per-wave body: 16 rows x 128 cols at row base r0w.
// MODE 1: A f32 (in-reg cvt).  MODE 2: A bf16 + relu(A+bias) on load.
// ---------------------------------------------------------------------------
template<int MODE>
__device__ __forceinline__
void gemm_rows(const void* __restrict__ Asrc, const ushort16* __restrict__ Wt,
               const float* __restrict__ bias, int M,
               ushort16* __restrict__ outB, int r0w) {
    const int lane = threadIdx.x & 63;
    const int l15 = lane & 15;
    const int quad = lane >> 4;

    int arow = r0w + l15;
    if (arow >= M) arow = M - 1;

    short8 afr[4];
    if (MODE == 1) {
        const float* ap = (const float*)Asrc + (size_t)arow * 128 + quad * 8;
#pragma unroll
        for (int kt = 0; kt < 4; ++kt) {
            float4 a0 = *(const float4*)(ap + kt * 32);
            float4 a1 = *(const float4*)(ap + kt * 32 + 4);
            short8 f;
            f[0] = (short)f2bf(a0.x); f[1] = (short)f2bf(a0.y);
            f[2] = (short)f2bf(a0.z); f[3] = (short)f2bf(a0.w);
            f[4] = (short)f2bf(a1.x); f[5] = (short)f2bf(a1.y);
            f[6] = (short)f2bf(a1.z); f[7] = (short)f2bf(a1.w);
            afr[kt] = f;
        }
    } else {
        const ushort16* aptr = (const ushort16*)Asrc + (size_t)arow * 128 + quad * 8;
#pragma unroll
        for (int kt = 0; kt < 4; ++kt) {
            uint4 v = *(const uint4*)(aptr + kt * 32);
            const float* bb = bias + kt * 32 + quad * 8;
            float4 b0 = *(const float4*)bb;
            float4 b1 = *(const float4*)(bb + 4);
            uint32 w0 = pack2(fmaxf(bflo(v.x) + b0.x, 0.f), fmaxf(bfhi(v.x) + b0.y, 0.f));
            uint32 w1 = pack2(fmaxf(bflo(v.y) + b0.z, 0.f), fmaxf(bfhi(v.y) + b0.w, 0.f));
            uint32 w2 = pack2(fmaxf(bflo(v.z) + b1.x, 0.f), fmaxf(bfhi(v.z) + b1.y, 0.f));
            uint32 w3 = pack2(fmaxf(bflo(v.w) + b1.z, 0.f), fmaxf(bfhi(v.w) + b1.w, 0.f));
            U16 u; u.u = make_uint4(w0, w1, w2, w3);
            afr[kt] = u.s;
        }
    }

    f32x4 acc[8];
#pragma unroll
    for (int t = 0; t < 8; ++t) acc[t] = (f32x4){0.f, 0.f, 0.f, 0.f};

#pragma unroll
    for (int t = 0; t < 8; ++t) {
        const ushort16* bptr = Wt + (size_t)(16 * t + l15) * 128 + quad * 8;
        short8 b0 = ld_frag(bptr);
        short8 b1 = ld_frag(bptr + 32);
        short8 b2 = ld_frag(bptr + 64);
        short8 b3 = ld_frag(bptr + 96);
        acc[t] = __builtin_amdgcn_mfma_f32_16x16x32_bf16(afr[0], b0, acc[t], 0, 0, 0);
        acc[t] = __builtin_amdgcn_mfma_f32_16x16x32_bf16(afr[1], b1, acc[t], 0, 0, 0);
        acc[t] = __builtin_amdgcn_mfma_f32_16x16x32_bf16(afr[2], b2, acc[t], 0, 0, 0);
        acc[t] = __builtin_amdgcn_mfma_f32_16x16x32_bf16(afr[3], b3, acc[t], 0, 0, 0);
    }

#pragma unroll
    for (int t = 0; t < 8; ++t) {
        float ov[4];
        ov[0] = acc[t].x; ov[1] = acc[t].y; ov[2] = acc[t].z; ov[3] = acc[t].w;
#pragma unroll
        for (int r = 0; r < 4; ++r) {
            float nb = __shfl_xor(ov[r], 1, 64);
            int row = r0w + quad * 4 + r;
            if (((l15 & 1) == 0) && row < M) {
                *(uint32*)(outB + (size_t)row * 128 + 16 * t + l15) = pack2(ov[r], nb);
            }
        }
    }
}

// ---------------------------------------------------------------------------
// K3: blocks < PB: scatter (src<<8|lt) into reserved per-block ranges;
//     blocks >= PB: GEMM1 (y = x @ W1, f32 in), 64 rows/block.
// ---------------------------------------------------------------------------
__global__ __launch_bounds__(256)
void scatter_gemm1_kernel(const int* __restrict__ src, const int* __restrict__ tgt,
                          const int* __restrict__ hist, uint32* __restrict__ rlist,
                          int E, int PB, int R,
                          const float* __restrict__ x, const ushort16* __restrict__ Wt1,
                          int M, ushort16* __restrict__ ybuf) {
    int tid = threadIdx.x, blk = blockIdx.x;
    if (blk >= PB) {
        gemm_rows<1>(x, Wt1, nullptr, M, ybuf, (blk - PB) * 64 + (tid >> 6) * 16);
        return;
    }
    __shared__ int cb[RSTR];
    __shared__ int cnt[RSTR];
    for (int i = tid; i < RSTR; i += 256) {
        cnt[i] = 0;
        cb[i] = (i < R) ? hist[(size_t)blk * RSTR + i] : 0;
    }
    __syncthreads();
    int q0 = blk * (CHP / 4), q1 = min(q0 + CHP / 4, E / 4);
    for (int q = q0 + tid; q < q1; q += 256) {
        int4 t = ((const int4*)tgt)[q];
        int4 s = ((const int4*)src)[q];
        int r0 = t.x >> 8, r1 = t.y >> 8, r2 = t.z >> 8, r3 = t.w >> 8;
        int p0 = cb[r0] + atomicAdd(&cnt[r0], 1);
        int p1 = cb[r1] + atomicAdd(&cnt[r1], 1);
        int p2 = cb[r2] + atomicAdd(&cnt[r2], 1);
        int p3 = cb[r3] + atomicAdd(&cnt[r3], 1);
        if (p0 < CAPP) rlist[(size_t)r0 * CAPP + p0] = ((uint32)s.x << 8) | (uint32)(t.x & 255);
        if (p1 < CAPP) rlist[(size_t)r1 * CAPP + p1] = ((uint32)s.y << 8) | (uint32)(t.y & 255);
        if (p2 < CAPP) rlist[(size_t)r2 * CAPP + p2] = ((uint32)s.z << 8) | (uint32)(t.z & 255);
        if (p3 < CAPP) rlist[(size_t)r3 * CAPP + p3] = ((uint32)s.w << 8) | (uint32)(t.w & 255);
    }
    if (blk == 0 && tid == 0) {
        for (int e = (E / 4) * 4; e < E; ++e) {
            int t = tgt[e], r = t >> 8;
            int p = cb[r] + atomicAdd(&cnt[r], 1);
            if (p < CAPP) rlist[(size_t)r * CAPP + p] = ((uint32)src[e] << 8) | (uint32)(t & 255);
        }
    }
}

// ---------------------------------------------------------------------------
// K4/K6: push-agg. One block per 256-node region; LDS f32 accumulator;
// two feature-half passes. out = in_t + (sum_{s->t} in_s) / max(deg,1).
// ---------------------------------------------------------------------------
#define PUSH_ADD(vv)                                            \
    {                                                           \
        float* a = &acc[lt][l8 * 8];                            \
        atomicAdd(&a[0], bflo(vv.x)); atomicAdd(&a[1], bfhi(vv.x)); \
        atomicAdd(&a[2], bflo(vv.y)); atomicAdd(&a[3], bfhi(vv.y)); \
        atomicAdd(&a[4], bflo(vv.z)); atomicAdd(&a[5], bfhi(vv.z)); \
        atomicAdd(&a[6], bflo(vv.w)); atomicAdd(&a[7], bfhi(vv.w)); \
    }

__global__ __launch_bounds__(1024)
void push_agg_kernel(const ushort16* __restrict__ in, const uint32* __restrict__ rlist,
                     const int* __restrict__ total, uint32* __restrict__ outb, int N) {
    __shared__ float acc[NRG2][65];
    __shared__ float invd[NRG2];
    __shared__ int degl[NRG2];
    __shared__ int countSh;
    int tid = threadIdx.x;
    int r = blockIdx.x;
    if (tid == 0) countSh = min(total[r], CAPP);
    {
        float* af = &acc[0][0];
        for (int i = tid; i < NRG2 * 65; i += 1024) af[i] = 0.f;
    }
    if (tid < NRG2) degl[tid] = 0;
    __syncthreads();
    int count = countSh;
    const uint32* rl = rlist + (size_t)r * CAPP;
    int t0 = r << 8;
    int nloc = min(N - t0, NRG2);
    int lane = tid & 63;
    int wv = tid >> 6;
    int grp = lane >> 3, l8 = lane & 7;

    // ---- pass A: features 0..63 (+ deg count)
    for (int i = wv * 16; i < count; i += 1024 / 64 * 16) {
        int i0 = i + grp, i1 = i + 8 + grp;
        bool ok0 = i0 < count, ok1 = i1 < count;
        uint32 e0 = ok0 ? rl[i0] : 0u;
        uint32 e1 = ok1 ? rl[i1] : 0u;
        uint4 v0, v1;
        if (ok0) v0 = *(const uint4*)(in + (size_t)(e0 >> 8) * 128 + l8 * 8);
        if (ok1) v1 = *(const uint4*)(in + (size_t)(e1 >> 8) * 128 + l8 * 8);
        if (ok0) {
            int lt = (int)(e0 & 255u);
            PUSH_ADD(v0);
            if (l8 == 0) atomicAdd(&degl[lt], 1);
        }
        if (ok1) {
            int lt = (int)(e1 & 255u);
            PUSH_ADD(v1);
            if (l8 == 0) atomicAdd(&degl[lt], 1);
        }
    }
    __syncthreads();
    if (tid < NRG2) invd[tid] = 1.f / fmaxf((float)degl[tid], 1.f);
    __syncthreads();
    // write features 0..63
    for (int idx = tid; idx < nloc * 8; idx += 1024) {
        int node = idx >> 3, q = idx & 7;
        uint4 vin = *(const uint4*)(in + (size_t)(t0 + node) * 128 + q * 8);
        float iv = invd[node];
        const float* a = &acc[node][q * 8];
        uint4 o;
        o.x = pack2(bflo(vin.x) + a[0] * iv, bfhi(vin.x) + a[1] * iv);
        o.y = pack2(bflo(vin.y) + a[2] * iv, bfhi(vin.y) + a[3] * iv);
        o.z = pack2(bflo(vin.z) + a[4] * iv, bfhi(vin.z) + a[5] * iv);
        o.w = pack2(bflo(vin.w) + a[6] * iv, bfhi(vin.w) + a[7] * iv);
        *(uint4*)(outb + (size_t)(t0 + node) * 64 + q * 4) = o;
    }
    __syncthreads();
    {
        float* af = &acc[0][0];
        for (int i = tid; i < NRG2 * 65; i += 1024) af[i] = 0.f;
    }
    __syncthreads();

    // ---- pass B: features 64..127
    for (int i = wv * 16; i < count; i += 1024 / 64 * 16) {
        int i0 = i + grp, i1 = i + 8 + grp;
        bool ok0 = i0 < count, ok1 = i1 < count;
        uint32 e0 = ok0 ? rl[i0] : 0u;
        uint32 e1 = ok1 ? rl[i1] : 0u;
        uint4 v0, v1;
        if (ok0) v0 = *(const uint4*)(in + (size_t)(e0 >> 8) * 128 + 64 + l8 * 8);
        if (ok1) v1 = *(const uint4*)(in + (size_t)(e1 >> 8) * 128 + 64 + l8 * 8);
        if (ok0) {
            int lt = (int)(e0 & 255u);
            PUSH_ADD(v0);
        }
        if (ok1) {
            int lt = (int)(e1 & 255u);
            PUSH_ADD(v1);
        }
    }
    __syncthreads();
    // write features 64..127
    for (int idx = tid; idx < nloc * 8; idx += 1024) {
        int node = idx >> 3, q = idx & 7;
        uint4 vin = *(const uint4*)(in + (size_t)(t0 + node) * 128 + 64 + q * 8);
        float iv = invd[node];
        const float* a = &acc[node][q * 8];
        uint4 o;
        o.x = pack2(bflo(vin.x) + a[0] * iv, bfhi(vin.x) + a[1] * iv);
        o.y = pack2(bflo(vin.y) + a[2] * iv, bfhi(vin.y) + a[3] * iv);
        o.z = pack2(bflo(vin.z) + a[4] * iv, bfhi(vin.z) + a[5] * iv);
        o.w = pack2(bflo(vin.w) + a[6] * iv, bfhi(vin.w) + a[7] * iv);
        *(uint4*)(outb + (size_t)(t0 + node) * 64 + 32 + q * 4) = o;
    }
}

// K5: z = relu(A + b1) @ W2 (bias-relu fused into A-load), 256t.
__global__ __launch_bounds__(256)
void gemm_biasrelu_kernel(const ushort16* __restrict__ A, const ushort16* __restrict__ Wt,
                          const float* __restrict__ bias, int M,
                          ushort16* __restrict__ outB) {
    gemm_rows<2>(A, Wt, bias, M, outB, blockIdx.x * 64 + ((threadIdx.x >> 6)) * 16);
}

// ---------------------------------------------------------------------------
// K7: projection, thread-per-node: out[n] = relu(w[n]+b2) @ Wp + bp.
// ---------------------------------------------------------------------------
__global__ __launch_bounds__(256)
void proj_kernel(const ushort16* __restrict__ w, const float* __restrict__ b2,
                 const float* __restrict__ Wp, const float* __restrict__ bp,
                 float* __restrict__ out, int N) {
    __shared__ float wps[640];
    __shared__ float b2s[128];
    int tid = threadIdx.x;
    for (int i = tid; i < 640; i += 256) wps[i] = Wp[i];
    if (tid < 128) b2s[tid] = b2[tid];
    __syncthreads();
    int n = blockIdx.x * 256 + tid;
    if (n >= N) return;
    const uint4* row = (const uint4*)(w + (size_t)n * 128);
    float p0 = 0.f, p1 = 0.f, p2 = 0.f, p3 = 0.f, p4 = 0.f;
#pragma unroll
    for (int q = 0; q < 16; ++q) {
        uint4 v = row[q];
        int c = q * 8;
        uint32 ww[4] = {v.x, v.y, v.z, v.w};
#pragma unroll
        for (int k = 0; k < 4; ++k) {
            float hlo = fmaxf(bflo(ww[k]) + b2s[c + 2 * k],     0.f);
            float hhi = fmaxf(bfhi(ww[k]) + b2s[c + 2 * k + 1], 0.f);
            const float* wl = &wps[(c + 2 * k) * 5];
            p0 += hlo * wl[0] + hhi * wl[5];
            p1 += hlo * wl[1] + hhi * wl[6];
            p2 += hlo * wl[2] + hhi * wl[7];
            p3 += hlo * wl[3] + hhi * wl[8];
            p4 += hlo * wl[4] + hhi * wl[9];
        }
    }
    float* o = out + (size_t)n * 5;
    o[0] = p0 + bp[0];
    o[1] = p1 + bp[1];
    o[2] = p2 + bp[2];
    o[3] = p3 + bp[3];
    o[4] = p4 + bp[4];
}

extern "C" void kernel_launch(void* const* d_in, const int* in_sizes, int n_in,
                              void* d_out, int out_size, void* d_ws, size_t ws_size,
                              hipStream_t stream) {
    const float* x     = (const float*)d_in[0];
    const int*   edges = (const int*)d_in[1];
    const float* W1    = (const float*)d_in[2];
    const float* b1    = (const float*)d_in[3];
    const float* W2    = (const float*)d_in[4];
    const float* b2    = (const float*)d_in[5];
    const float* Wp    = (const float*)d_in[6];
    const float* bp    = (const float*)d_in[7];
    float* out = (float*)d_out;

    int N = in_sizes[0] / 128;   // 100000
    int E = in_sizes[1] / 2;     // 1600000
    const int* src = edges;
    const int* tgt = edges + E;

    const int R  = (N + NRG2 - 1) >> 8;      // regions (391)
    const int PB = (E + CHP - 1) / CHP;      // count/scatter blocks (391)

    char* ws = (char*)d_ws;
    size_t off = 0;
    auto alloc = [&](size_t bytes) {
        char* p = ws + off;
        off = (off + bytes + 255) & ~(size_t)255;
        return p;
    };
    int*      hist    = (int*)alloc((size_t)PB * RSTR * 4);
    int*      total   = (int*)alloc((size_t)RSTR * 4);
    uint32*   rlist   = (uint32*)alloc((size_t)R * CAPP * 4);   // 8.0 MB
    ushort16* ybuf    = (ushort16*)alloc((size_t)N * 128 * 2);  // y, later z
    ushort16* abuf    = (ushort16*)alloc((size_t)N * 128 * 2);  // a1, later w
    ushort16* Wt1     = (ushort16*)alloc(128 * 128 * 2);
    ushort16* Wt2     = (ushort16*)alloc(128 * 128 * 2);
    (void)ws_size;

    const int gemmBlocks = (N + 63) / 64;        // 1563
    const int projBlocks = (N + 255) / 256;      // 391

    // K1: region count (391 blocks) + Wt prep (16 blocks)
    count_prep_kernel<<<PB + 16, 256, 0, stream>>>(tgt, hist, W1, W2, Wt1, Wt2,
                                                   E, PB, R);
    // K2: per-region column scan -> per-block bases + total
    scan_kernel<<<R, 256, 0, stream>>>(hist, total, PB);
    // K3: scatter packed rlist (391 blocks) || y = x @ W1 (1563 blocks)
    scatter_gemm1_kernel<<<PB + gemmBlocks, 256, 0, stream>>>(src, tgt, hist, rlist,
                                                              E, PB, R, x, Wt1,
                                                              N, ybuf);
    // K4: a1 = y + mean_agg(y)  (push, LDS accumulator)
    push_agg_kernel<<<R, 1024, 0, stream>>>(ybuf, rlist, total, (uint32*)abuf, N);
    // K5: z = relu(a1 + b1) @ W2  (bias-relu in A-load; reuse ybuf)
    gemm_biasrelu_kernel<<<gemmBlocks, 256, 0, stream>>>(abuf, Wt2, b1, N, ybuf);
    // K6: w = z + mean_agg(z)  (push; reuse abuf)
    push_agg_kernel<<<R, 1024, 0, stream>>>(ybuf, rlist, total, (uint32*)abuf, N);
    // K7: out = relu(w + b2) @ Wp + bp
    proj_kernel<<<projBlocks, 256, 0, stream>>>(abuf, b2, Wp, bp, out, N);
}

// Round 14
// 325.613 us; speedup vs baseline: 8.9644x; 8.9644x over previous
//
#include <hip/hip_runtime.h>

typedef unsigned int uint32;
typedef unsigned short ushort16;

typedef __attribute__((ext_vector_type(8))) short short8;
typedef __attribute__((ext_vector_type(4))) float f32x4;

// ---------------------------------------------------------------------------
// GNN: h1 = relu((x + mean_agg(x)) @ W1 + b1)
//      h2 = relu((h1 + mean_agg(h1)) @ W2 + b2)
//      out = h2 @ Wp + bp
//
// R25: revert to champion (R17, measured 325.27us @ Round 6).
//  R24 post-mortem: push-style LDS-f32-atomic aggregation = 1369us/pass
//  (12.8M LDS atomics serialize; VALU 1%, HBM 2%). Pull/CSR is structurally
//  right on this chip. Six structural experiments since R17 (nt-stores,
//  merged reservation, deg-atomic chain, 1-pass CSR, coarse prep, push-agg)
//  all measured worse/neutral; locking in the best verified kernel.
//  Structure (R17): commute y=x@W1 -> h1=relu(y+agg(y)+b1) etc.
//   K1a count (782 blks CH=2048, LDS cnt[49]) + Wt prep (16 blks, float4)
//   K1b scan (49 blks, column scan over 782)
//   K1c scatter (782 blks, reserved ranges, no global atomics)
//   K2  csr build (49 blks, 4x-unrolled 2-pass) || GEMM1 (391 blks) @1024t
//   K3  agg1+bias+relu fused | K4 gemm2 raw | K5 agg2+bias+relu+proj fused
// ---------------------------------------------------------------------------

#define RSH 11                 // 2048 nodes per region
#define NRG 2048               // nodes per region
#define CAP 49152              // rlist capacity per region (avg 32.7K)
#define CH  2048               // edges per partition block

__device__ __forceinline__ ushort16 f2bf(float f) {
    uint32 u = __float_as_uint(f);
    u += 0x7fffu + ((u >> 16) & 1u);       // round-to-nearest-even
    return (ushort16)(u >> 16);
}
__device__ __forceinline__ float bfhi(uint32 u) { return __uint_as_float(u & 0xffff0000u); }
__device__ __forceinline__ float bflo(uint32 u) { return __uint_as_float(u << 16); }
__device__ __forceinline__ uint32 pack2(float a, float b) {
    return (uint32)f2bf(a) | ((uint32)f2bf(b) << 16);
}

union U16 { uint4 u; short8 s; };
__device__ __forceinline__ short8 ld_frag(const ushort16* p) {
    U16 x; x.u = *(const uint4*)p; return x.s;
}

#define ACC8(v) \
    acc[0] += bflo(v.x); acc[1] += bfhi(v.x); \
    acc[2] += bflo(v.y); acc[3] += bfhi(v.y); \
    acc[4] += bflo(v.z); acc[5] += bfhi(v.z); \
    acc[6] += bflo(v.w); acc[7] += bfhi(v.w);

// ---------------------------------------------------------------------------
// K1a: per-block region count (LDS only) + Wt prep on 16 extra blocks.
// ---------------------------------------------------------------------------
__global__ __launch_bounds__(256)
void count_prep_kernel(const int* __restrict__ tgt, int* __restrict__ hist,
                       const float* __restrict__ W1, const float* __restrict__ W2,
                       ushort16* __restrict__ Wt1, ushort16* __restrict__ Wt2,
                       int E, int PB, int R) {
    int tid = threadIdx.x, blk = blockIdx.x;
    if (blk >= PB) {   // Wt prep: 16 blocks, 2048 floats each, float4 loads
        int idx = blk - PB;
        const float* W = (idx >> 3) ? W2 : W1;
        ushort16* Wt = (idx >> 3) ? Wt2 : Wt1;
        int i0 = (idx & 7) * 2048 + tid * 8;
        float4 a = *(const float4*)(W + i0);
        float4 b = *(const float4*)(W + i0 + 4);
        int k = i0 >> 7, col = i0 & 127;
        Wt[(col + 0) * 128 + k] = f2bf(a.x);
        Wt[(col + 1) * 128 + k] = f2bf(a.y);
        Wt[(col + 2) * 128 + k] = f2bf(a.z);
        Wt[(col + 3) * 128 + k] = f2bf(a.w);
        Wt[(col + 4) * 128 + k] = f2bf(b.x);
        Wt[(col + 5) * 128 + k] = f2bf(b.y);
        Wt[(col + 6) * 128 + k] = f2bf(b.z);
        Wt[(col + 7) * 128 + k] = f2bf(b.w);
        return;
    }
    __shared__ int cnt[64];
    __shared__ int cbase[64];
    (void)cbase;
    if (tid < 64) cnt[tid] = 0;
    __syncthreads();
    int q0 = blk * (CH / 4), q1 = min(q0 + CH / 4, E / 4);
    for (int q = q0 + tid; q < q1; q += 256) {
        int4 t = ((const int4*)tgt)[q];
        atomicAdd(&cnt[t.x >> RSH], 1);
        atomicAdd(&cnt[t.y >> RSH], 1);
        atomicAdd(&cnt[t.z >> RSH], 1);
        atomicAdd(&cnt[t.w >> RSH], 1);
    }
    if (blk == 0 && tid == 0)
        for (int e = (E / 4) * 4; e < E; ++e) atomicAdd(&cnt[tgt[e] >> RSH], 1);
    __syncthreads();
    if (tid < R) hist[(size_t)blk * 64 + tid] = cnt[tid];
}

// ---------------------------------------------------------------------------
// K1b: per-region exclusive column scan of hist over PB blocks + total[r].
// ---------------------------------------------------------------------------
__global__ __launch_bounds__(256)
void scan_kernel(int* __restrict__ hist, int* __restrict__ total, int PB) {
    __shared__ int sd[256];
    __shared__ int carrySh;
    int r = blockIdx.x, tid = threadIdx.x;
    if (tid == 0) carrySh = 0;
    __syncthreads();
    int chunks = (PB + 255) >> 8;
    for (int ch = 0; ch < chunks; ++ch) {
        int g = ch * 256 + tid;
        int v = (g < PB) ? hist[(size_t)g * 64 + r] : 0;
        int c0 = carrySh;
        sd[tid] = v;
        __syncthreads();
        for (int o = 1; o < 256; o <<= 1) {
            int t = (tid >= o) ? sd[tid - o] : 0;
            __syncthreads();
            sd[tid] += t;
            __syncthreads();
        }
        if (g < PB) hist[(size_t)g * 64 + r] = sd[tid] - v + c0;
        int tot = sd[255];
        __syncthreads();
        if (tid == 0) carrySh = c0 + tot;
        __syncthreads();
    }
    if (tid == 0) total[r] = carrySh;
}

// ---------------------------------------------------------------------------
// K1c: scatter (src,tgt) into reserved per-block ranges of per-region lists.
// ---------------------------------------------------------------------------
__global__ __launch_bounds__(256)
void scatter_kernel(const int* __restrict__ src, const int* __restrict__ tgt,
                    const int* __restrict__ hist, uint2* __restrict__ rlist,
                    int E, int R) {
    __shared__ int cb[64];
    __shared__ int cnt[64];
    int tid = threadIdx.x, blk = blockIdx.x;
    if (tid < 64) {
        cnt[tid] = 0;
        cb[tid] = (tid < R) ? hist[(size_t)blk * 64 + tid] : 0;
    }
    __syncthreads();
    int q0 = blk * (CH / 4), q1 = min(q0 + CH / 4, E / 4);
    for (int q = q0 + tid; q < q1; q += 256) {
        int4 t = ((const int4*)tgt)[q];
        int4 s = ((const int4*)src)[q];
        int r0 = t.x >> RSH, r1 = t.y >> RSH, r2 = t.z >> RSH, r3 = t.w >> RSH;
        int p0 = cb[r0] + atomicAdd(&cnt[r0], 1);
        int p1 = cb[r1] + atomicAdd(&cnt[r1], 1);
        int p2 = cb[r2] + atomicAdd(&cnt[r2], 1);
        int p3 = cb[r3] + atomicAdd(&cnt[r3], 1);
        if (p0 < CAP) rlist[(size_t)r0 * CAP + p0] = make_uint2((uint32)s.x, (uint32)t.x);
        if (p1 < CAP) rlist[(size_t)r1 * CAP + p1] = make_uint2((uint32)s.y, (uint32)t.y);
        if (p2 < CAP) rlist[(size_t)r2 * CAP + p2] = make_uint2((uint32)s.z, (uint32)t.z);
        if (p3 < CAP) rlist[(size_t)r3 * CAP + p3] = make_uint2((uint32)s.w, (uint32)t.w);
    }
    if (blk == 0 && tid == 0) {
        for (int e = (E / 4) * 4; e < E; ++e) {
            int t = tgt[e], r = t >> RSH;
            int p = cb[r] + atomicAdd(&cnt[r], 1);
            if (p < CAP) rlist[(size_t)r * CAP + p] = make_uint2((uint32)src[e], (uint32)t);
        }
    }
}

// ---------------------------------------------------------------------------
// GEMM per-wave body: 16 rows x 128 cols at row base r0w.
// INF32: A f32 (in-register bf16 cvt); else A bf16 row-major.
// ---------------------------------------------------------------------------
template<int INF32>
__device__ __forceinline__
void gemm_rows(const void* __restrict__ Asrc, const ushort16* __restrict__ Wt,
               int M, ushort16* __restrict__ outB, int r0w) {
    const int lane = threadIdx.x & 63;
    const int l15 = lane & 15;
    const int quad = lane >> 4;

    int arow = r0w + l15;
    if (arow >= M) arow = M - 1;

    short8 afr[4];
    if (INF32) {
        const float* ap = (const float*)Asrc + (size_t)arow * 128 + quad * 8;
#pragma unroll
        for (int kt = 0; kt < 4; ++kt) {
            float4 a0 = *(const float4*)(ap + kt * 32);
            float4 a1 = *(const float4*)(ap + kt * 32 + 4);
            short8 f;
            f[0] = (short)f2bf(a0.x); f[1] = (short)f2bf(a0.y);
            f[2] = (short)f2bf(a0.z); f[3] = (short)f2bf(a0.w);
            f[4] = (short)f2bf(a1.x); f[5] = (short)f2bf(a1.y);
            f[6] = (short)f2bf(a1.z); f[7] = (short)f2bf(a1.w);
            afr[kt] = f;
        }
    } else {
        const ushort16* aptr = (const ushort16*)Asrc + (size_t)arow * 128 + quad * 8;
#pragma unroll
        for (int kt = 0; kt < 4; ++kt) afr[kt] = ld_frag(aptr + kt * 32);
    }

    f32x4 acc[8];
#pragma unroll
    for (int t = 0; t < 8; ++t) acc[t] = (f32x4){0.f, 0.f, 0.f, 0.f};

#pragma unroll
    for (int t = 0; t < 8; ++t) {
        const ushort16* bptr = Wt + (size_t)(16 * t + l15) * 128 + quad * 8;
        short8 b0 = ld_frag(bptr);
        short8 b1 = ld_frag(bptr + 32);
        short8 b2 = ld_frag(bptr + 64);
        short8 b3 = ld_frag(bptr + 96);
        acc[t] = __builtin_amdgcn_mfma_f32_16x16x32_bf16(afr[0], b0, acc[t], 0, 0, 0);
        acc[t] = __builtin_amdgcn_mfma_f32_16x16x32_bf16(afr[1], b1, acc[t], 0, 0, 0);
        acc[t] = __builtin_amdgcn_mfma_f32_16x16x32_bf16(afr[2], b2, acc[t], 0, 0, 0);
        acc[t] = __builtin_amdgcn_mfma_f32_16x16x32_bf16(afr[3], b3, acc[t], 0, 0, 0);
    }

#pragma unroll
    for (int t = 0; t < 8; ++t) {
        float ov[4];
        ov[0] = acc[t].x; ov[1] = acc[t].y; ov[2] = acc[t].z; ov[3] = acc[t].w;
#pragma unroll
        for (int r = 0; r < 4; ++r) {
            float nb = __shfl_xor(ov[r], 1, 64);
            int row = r0w + quad * 4 + r;
            if (((l15 & 1) == 0) && row < M) {
                *(uint32*)(outB + (size_t)row * 128 + 16 * t + l15) = pack2(ov[r], nb);
            }
        }
    }
}

// ---------------------------------------------------------------------------
// K2 (1024t): blocks < R: per-region CSR build; blocks >= R: GEMM1 (f32 in).
// ---------------------------------------------------------------------------
__global__ __launch_bounds__(1024)
void csr_gemm1_kernel(const uint2* __restrict__ rlist, const int* __restrict__ total,
                      int* __restrict__ start, int* __restrict__ deg,
                      int* __restrict__ csr, int N, int R,
                      const float* __restrict__ x, const ushort16* __restrict__ Wt1,
                      ushort16* __restrict__ ybuf) {
    int blk = blockIdx.x;
    int tid = threadIdx.x;
    if (blk >= R) {
        int gid = blk - R;
        gemm_rows<1>(x, Wt1, N, ybuf, gid * 256 + (tid >> 6) * 16);
        return;
    }
    __shared__ int hist[NRG];
    __shared__ int sd[1024];
    __shared__ int carrySh;
    __shared__ int rbaseSh, countSh;

    int r = blk;
    if (tid == 0) countSh = min(total[r], CAP);
    if (tid < 64) {   // wave 0: rbase = sum of totals of earlier regions (R<=64)
        int v = (tid < R) ? total[tid] : 0;
        int pm = (tid < r) ? v : 0;
#pragma unroll
        for (int o = 1; o < 64; o <<= 1) pm += __shfl_xor(pm, o, 64);
        if (tid == 0) rbaseSh = pm;
    }
    for (int i = tid; i < NRG; i += 1024) hist[i] = 0;
    __syncthreads();
    int count = countSh;
    const uint2* rl = rlist + (size_t)r * CAP;
    int n0 = r << RSH;

    // pass 1: degree histogram, 4x unrolled
    {
        int i = tid;
        for (; i + 3072 < count; i += 4096) {
            uint2 a = rl[i], b = rl[i + 1024], c = rl[i + 2048], d = rl[i + 3072];
            atomicAdd(&hist[a.y & (NRG - 1)], 1);
            atomicAdd(&hist[b.y & (NRG - 1)], 1);
            atomicAdd(&hist[c.y & (NRG - 1)], 1);
            atomicAdd(&hist[d.y & (NRG - 1)], 1);
        }
        for (; i < count; i += 1024)
            atomicAdd(&hist[rl[i].y & (NRG - 1)], 1);
    }
    __syncthreads();

    // exclusive scan of 2048 in 2 chunks of 1024; emit start/deg; hist->cursor
    if (tid == 0) carrySh = rbaseSh;
    __syncthreads();
    for (int ch = 0; ch < 2; ++ch) {
        int idx = ch * 1024 + tid;
        int v = hist[idx];
        int c0 = carrySh;
        sd[tid] = v;
        __syncthreads();
        for (int o = 1; o < 1024; o <<= 1) {
            int t = (tid >= o) ? sd[tid - o] : 0;
            __syncthreads();
            sd[tid] += t;
            __syncthreads();
        }
        int excl = sd[tid] - v + c0;
        int tot = sd[1023];
        int node = n0 + idx;
        if (node < N) { start[node] = excl; deg[node] = v; }
        __syncthreads();
        hist[idx] = excl;   // becomes scatter cursor
        if (tid == 0) carrySh = c0 + tot;
        __syncthreads();
    }

    // pass 2: scatter into own csr window, 4x unrolled
    {
        int i = tid;
        for (; i + 3072 < count; i += 4096) {
            uint2 a = rl[i], b = rl[i + 1024], c = rl[i + 2048], d = rl[i + 3072];
            int pa = atomicAdd(&hist[a.y & (NRG - 1)], 1);
            int pb = atomicAdd(&hist[b.y & (NRG - 1)], 1);
            int pc = atomicAdd(&hist[c.y & (NRG - 1)], 1);
            int pd = atomicAdd(&hist[d.y & (NRG - 1)], 1);
            csr[pa] = (int)a.x;
            csr[pb] = (int)b.x;
            csr[pc] = (int)c.x;
            csr[pd] = (int)d.x;
        }
        for (; i < count; i += 1024) {
            uint2 e = rl[i];
            int p = atomicAdd(&hist[e.y & (NRG - 1)], 1);
            csr[p] = (int)e.x;
        }
    }
}

// standalone GEMM (layer 2), 256 threads
template<int INF32>
__global__ __launch_bounds__(256)
void gemm_raw_kernel(const void* __restrict__ Asrc, const ushort16* __restrict__ Wt,
                     int M, ushort16* __restrict__ outB) {
    gemm_rows<INF32>(Asrc, Wt, M, outB, blockIdx.x * 64 + (threadIdx.x >> 6) * 16);
}

// ---------------------------------------------------------------------------
// agg + epilogue: h = relu(in_t + mean_{s in N(t)} in_s + bias)
// PROJ=0: write h bf16 row-major.  PROJ=1: out_t = h @ Wp + bp (f32 [N,5]).
// One wave per node; 8 edges in flight.
// ---------------------------------------------------------------------------
template<int PROJ>
__global__ __launch_bounds__(256, 4)
void agg_fuse_kernel(const ushort16* __restrict__ hb,
                     const int* __restrict__ start, const int* __restrict__ degv,
                     const int* __restrict__ csr,
                     const float* __restrict__ bias,
                     uint32* __restrict__ outb,
                     const float* __restrict__ Wp, const float* __restrict__ bp,
                     float* __restrict__ outP, int N) {
    int wid = (blockIdx.x * 256 + threadIdx.x) >> 6;
    int lane = threadIdx.x & 63;
    if (wid >= N) return;
    int g = lane >> 4, sl = lane & 15;
    int s0 = start[wid];
    int deg = degv[wid];
    int fi = sl * 4 + g;
    uint32 su = ((const uint32*)hb)[(size_t)wid * 64 + fi];

    float acc[8];
#pragma unroll
    for (int j = 0; j < 8; ++j) acc[j] = 0.f;

    int base = 0;
    for (; base + 8 <= deg; base += 8) {
        int i0 = csr[s0 + base + g];
        int i1 = csr[s0 + base + 4 + g];
        uint4 v0 = *(const uint4*)(hb + (size_t)i0 * 128 + sl * 8);
        uint4 v1 = *(const uint4*)(hb + (size_t)i1 * 128 + sl * 8);
        ACC8(v0); ACC8(v1);
    }
    for (; base < deg; base += 4) {
        int e = base + g;
        if (e < deg) {
            int s = csr[s0 + e];
            uint4 v = *(const uint4*)(hb + (size_t)s * 128 + sl * 8);
            ACC8(v);
        }
    }
#pragma unroll
    for (int j = 0; j < 8; ++j) {
        acc[j] += __shfl_xor(acc[j], 16, 64);
        acc[j] += __shfl_xor(acc[j], 32, 64);
    }
    float inv = 1.f / fmaxf((float)deg, 1.f);
    float ax = (g == 0) ? acc[0] : (g == 1) ? acc[2] : (g == 2) ? acc[4] : acc[6];
    float ay = (g == 0) ? acc[1] : (g == 1) ? acc[3] : (g == 2) ? acc[5] : acc[7];

    float ha = fmaxf(bflo(su) + ax * inv + bias[2 * fi],     0.f);
    float hc = fmaxf(bfhi(su) + ay * inv + bias[2 * fi + 1], 0.f);

    if (!PROJ) {
        outb[(size_t)wid * 64 + fi] = pack2(ha, hc);
    } else {
        float p[5];
#pragma unroll
        for (int j = 0; j < 5; ++j)
            p[j] = ha * Wp[(2 * fi) * 5 + j] + hc * Wp[(2 * fi + 1) * 5 + j];
#pragma unroll
        for (int m = 1; m <= 32; m <<= 1)
#pragma unroll
            for (int j = 0; j < 5; ++j) p[j] += __shfl_xor(p[j], m, 64);
        if (lane == 0) {
#pragma unroll
            for (int j = 0; j < 5; ++j) outP[(size_t)wid * 5 + j] = p[j] + bp[j];
        }
    }
}

extern "C" void kernel_launch(void* const* d_in, const int* in_sizes, int n_in,
                              void* d_out, int out_size, void* d_ws, size_t ws_size,
                              hipStream_t stream) {
    const float* x     = (const float*)d_in[0];
    const int*   edges = (const int*)d_in[1];
    const float* W1    = (const float*)d_in[2];
    const float* b1    = (const float*)d_in[3];
    const float* W2    = (const float*)d_in[4];
    const float* b2    = (const float*)d_in[5];
    const float* Wp    = (const float*)d_in[6];
    const float* bp    = (const float*)d_in[7];
    float* out = (float*)d_out;

    int N = in_sizes[0] / 128;   // 100000
    int E = in_sizes[1] / 2;     // 1600000
    const int* src = edges;
    const int* tgt = edges + E;

    const int R  = (N + NRG - 1) >> RSH;     // regions (49)
    const int PB = (E + CH - 1) / CH;        // partition blocks (782)

    char* ws = (char*)d_ws;
    size_t off = 0;
    auto alloc = [&](size_t bytes) {
        char* p = ws + off;
        off = (off + bytes + 255) & ~(size_t)255;
        return p;
    };
    int*      deg     = (int*)alloc((size_t)N * 4);
    int*      start   = (int*)alloc((size_t)N * 4);
    int*      csr     = (int*)alloc((size_t)E * 4);
    int*      hist    = (int*)alloc((size_t)PB * 64 * 4);
    int*      total   = (int*)alloc(64 * 4);
    ushort16* ybuf    = (ushort16*)alloc((size_t)N * 128 * 2);  // y, later z
    ushort16* h1      = (ushort16*)alloc((size_t)N * 128 * 2);
    ushort16* Wt1     = (ushort16*)alloc(128 * 128 * 2);
    ushort16* Wt2     = (ushort16*)alloc(128 * 128 * 2);
    uint2*    rlist   = (uint2*)alloc((size_t)R * CAP * 8);     // 19.3 MB
    (void)ws_size;

    const int g1Blocks   = (N + 255) / 256;      // 391 (1024-thr blocks)
    const int gemmBlocks = (N + 63) / 64;        // 1563
    const int aggBlocks  = (N + 3) / 4;          // 25000

    // K1a: region count (782 blocks) + Wt prep (16 blocks)
    count_prep_kernel<<<PB + 16, 256, 0, stream>>>(tgt, hist, W1, W2, Wt1, Wt2,
                                                   E, PB, R);
    // K1b: per-region column scan -> per-block bases + total
    scan_kernel<<<R, 256, 0, stream>>>(hist, total, PB);
    // K1c: scatter into per-region lists (reserved ranges, no global atomics)
    scatter_kernel<<<PB, 256, 0, stream>>>(src, tgt, hist, rlist, E, R);
    // K2: per-region CSR build (49 blocks)  ||  y = x @ W1 (391 blocks)
    csr_gemm1_kernel<<<R + g1Blocks, 1024, 0, stream>>>(rlist, total, start, deg,
                                                        csr, N, R, x, Wt1, ybuf);
    // K3: h1 = relu(y + agg(y) + b1)
    agg_fuse_kernel<0><<<aggBlocks, 256, 0, stream>>>(ybuf, start, deg, csr, b1,
                                                      (uint32*)h1, nullptr, nullptr,
                                                      nullptr, N);
    // K4: z = h1 @ W2 (bf16 in, bf16 out, reuse ybuf)
    gemm_raw_kernel<0><<<gemmBlocks, 256, 0, stream>>>(h1, Wt2, N, ybuf);
    // K5: h2 = relu(z + agg(z) + b2); out = h2 @ Wp + bp
    agg_fuse_kernel<1><<<aggBlocks, 256, 0, stream>>>(ybuf, start, deg, csr, b2,
                                                      nullptr, Wp, bp, out, N);
}